// Round 1
// baseline (2313.289 us; speedup 1.0000x reference)
//
#include <hip/hip_runtime.h>
#include <math.h>

#define T_LEN   2048
#define NB      256
#define N_FREQ  1024
#define DMODEL  64
#define HORIZON 720

// ws layout in floats
#define WS_AMP   0
#define WS_META  1024          // mi[0..3] ints (P1,cols1,P2,cols2), mf[4..5] floats (w1,w2)
#define WS_Y0    2048
#define WS_Y1    (2048 + NB * T_LEN)

#define KPB 4  // frequencies per block in DFT kernel

// ---------------------------------------------------------------------------
// Kernel 1: direct DFT amplitude spectrum, batch-averaged. amp[k-1] for k=1..1024
// ---------------------------------------------------------------------------
__global__ __launch_bounds__(256) void dft_amp_kernel(const float* __restrict__ x,
                                                      float* __restrict__ amp) {
    __shared__ float stab[2048];
    __shared__ float rew[4][KPB][NB];
    __shared__ float imw[4][KPB][NB];
    __shared__ float red[256];
    const int tid = threadIdx.x;
    for (int m = tid; m < 2048; m += 256)
        stab[m] = (float)sin((double)m * 3.0679615757712823e-3);  // 2*pi/2048
    __syncthreads();

    const int wave = tid >> 6, lane = tid & 63;
    const int kbase = blockIdx.x * KPB + 1;

    // hoist per-lane trig into registers (t = wave*512 + it*64 + lane)
    float cr[KPB][8], ci[KPB][8];
    #pragma unroll
    for (int kk = 0; kk < KPB; ++kk) {
        int k = kbase + kk;
        #pragma unroll
        for (int it = 0; it < 8; ++it) {
            int t = wave * 512 + it * 64 + lane;
            int m = (k * t) & 2047;
            cr[kk][it] = stab[(m + 512) & 2047];
            ci[kk][it] = stab[m];
        }
    }

    for (int b = 0; b < NB; ++b) {
        const float* xr = x + b * T_LEN + wave * 512 + lane;
        float v[8];
        #pragma unroll
        for (int it = 0; it < 8; ++it) v[it] = xr[it * 64];
        #pragma unroll
        for (int kk = 0; kk < KPB; ++kk) {
            float re = 0.f, im = 0.f;
            #pragma unroll
            for (int it = 0; it < 8; ++it) {
                re = fmaf(v[it], cr[kk][it], re);
                im = fmaf(v[it], ci[kk][it], im);
            }
            #pragma unroll
            for (int off = 32; off > 0; off >>= 1) {
                re += __shfl_xor(re, off);
                im += __shfl_xor(im, off);
            }
            if (lane == 0) { rew[wave][kk][b] = re; imw[wave][kk][b] = im; }
        }
    }
    __syncthreads();

    for (int kk = 0; kk < KPB; ++kk) {
        float re = rew[0][kk][tid] + rew[1][kk][tid] + rew[2][kk][tid] + rew[3][kk][tid];
        float im = imw[0][kk][tid] + imw[1][kk][tid] + imw[2][kk][tid] + imw[3][kk][tid];
        red[tid] = sqrtf(re * re + im * im);
        __syncthreads();
        for (int s = 128; s > 0; s >>= 1) {
            if (tid < s) red[tid] += red[tid + s];
            __syncthreads();
        }
        if (tid == 0) amp[kbase + kk - 1] = red[0] * (1.0f / 256.0f);
        __syncthreads();
    }
}

// ---------------------------------------------------------------------------
// Kernel 2: top-2 (value desc, tie -> lower index), derive periods + softmax wts
// ---------------------------------------------------------------------------
__global__ void topk_meta_kernel(const float* __restrict__ amp,
                                 int* __restrict__ mi, float* __restrict__ mf) {
    __shared__ float sv[256];
    __shared__ int   si[256];
    __shared__ float bpv[2];
    __shared__ int   bpi[2];
    const int tid = threadIdx.x;
    for (int pass = 0; pass < 2; ++pass) {
        int excl = (pass == 1) ? bpi[0] : -1;
        float bv = -1e30f; int bi = 1 << 30;
        for (int j = tid; j < N_FREQ; j += 256) {
            if (j == excl) continue;
            float v = amp[j];
            if (v > bv || (v == bv && j < bi)) { bv = v; bi = j; }
        }
        sv[tid] = bv; si[tid] = bi;
        __syncthreads();
        for (int s = 128; s > 0; s >>= 1) {
            if (tid < s) {
                if (sv[tid + s] > sv[tid] ||
                    (sv[tid + s] == sv[tid] && si[tid + s] < si[tid])) {
                    sv[tid] = sv[tid + s]; si[tid] = si[tid + s];
                }
            }
            __syncthreads();
        }
        if (tid == 0) { bpv[pass] = sv[0]; bpi[pass] = si[0]; }
        __syncthreads();
    }
    if (tid == 0) {
        float v1 = bpv[0], v2 = bpv[1];
        int f1 = bpi[0] + 1, f2 = bpi[1] + 1;
        int P1 = (int)llround(2048.0 / (double)f1); if (P1 < 1) P1 = 1;
        int P2 = (int)llround(2048.0 / (double)f2); if (P2 < 1) P2 = 1;
        mi[0] = P1; mi[1] = (T_LEN + P1 - 1) / P1;
        mi[2] = P2; mi[3] = (T_LEN + P2 - 1) / P2;
        float mx = fmaxf(v1, v2);
        float e1 = expf(v1 - mx), e2 = expf(v2 - mx);
        float inv = 1.0f / (e1 + e2);
        mf[4] = e1 * inv; mf[5] = e2 * inv;
    }
}

// ---------------------------------------------------------------------------
// Kernel 3: fused conv(1->64) -> GELU(tanh) -> conv(64->1) on (P, cols) image,
// 8x8 output tiles, grid-stride over data-dependent tile count.
// ---------------------------------------------------------------------------
__global__ __launch_bounds__(256) void conv_unit_kernel(
    const float* __restrict__ x,
    const float* __restrict__ w1, const float* __restrict__ b1,
    const float* __restrict__ w2, const float* __restrict__ b2,
    const int* __restrict__ mi, const float* __restrict__ mf,
    float* __restrict__ ws)
{
    const int per   = blockIdx.y;
    const int P     = mi[per * 2 + 0];
    const int cols  = mi[per * 2 + 1];
    const float wgt = mf[4 + per];
    float* yout = ws + (per == 0 ? WS_Y0 : WS_Y1);

    __shared__ float w1s[DMODEL * 9];
    __shared__ float w2s[DMODEL * 9];
    __shared__ float b1s[DMODEL];
    __shared__ float xs[12][13];
    __shared__ float hs[DMODEL][101];   // 10x10 h tile, stride 101 (pad)

    const int tid = threadIdx.x;
    for (int i = tid; i < DMODEL * 9; i += 256) { w1s[i] = w1[i]; w2s[i] = w2[i]; }
    if (tid < DMODEL) b1s[tid] = b1[tid];
    const float bias2 = b2[0];

    const int tp = (P + 7) >> 3;
    const int tc = (cols + 7) >> 3;
    const int tiles_img = tp * tc;
    const int total = tiles_img * NB;

    for (int tile = blockIdx.x; tile < total; tile += gridDim.x) {
        const int b   = tile / tiles_img;
        const int ti  = tile - b * tiles_img;
        const int tpi = ti / tc;
        const int tci = ti - tpi * tc;
        const int p0 = tpi * 8, c0 = tci * 8;

        __syncthreads();  // protect xs/hs (and first-iter weight loads)
        if (tid < 144) {
            int i = tid / 12, j = tid - (tid / 12) * 12;
            int p = p0 - 2 + i, c = c0 - 2 + j;
            float v = 0.f;
            if (p >= 0 && p < P && c >= 0 && c < cols) {
                int t = c * P + p;            // in-image; zero beyond T (time pad)
                if (t < T_LEN) v = x[b * T_LEN + t];
            }
            xs[i][j] = v;
        }
        __syncthreads();

        // conv1 + GELU -> hs (64 ch x 10x10 halo tile); zero outside image
        #pragma unroll
        for (int it = 0; it < 25; ++it) {
            int idx = it * 256 + tid;          // 0..6399 = ch*100 + px
            int ch = idx / 100;
            int px = idx - ch * 100;
            int pi = px / 10;
            int pj = px - pi * 10;
            const float* w = &w1s[ch * 9];
            float a = b1s[ch];
            a = fmaf(w[0], xs[pi    ][pj    ], a);
            a = fmaf(w[1], xs[pi    ][pj + 1], a);
            a = fmaf(w[2], xs[pi    ][pj + 2], a);
            a = fmaf(w[3], xs[pi + 1][pj    ], a);
            a = fmaf(w[4], xs[pi + 1][pj + 1], a);
            a = fmaf(w[5], xs[pi + 1][pj + 2], a);
            a = fmaf(w[6], xs[pi + 2][pj    ], a);
            a = fmaf(w[7], xs[pi + 2][pj + 1], a);
            a = fmaf(w[8], xs[pi + 2][pj + 2], a);
            // tanh-approx GELU (matches jax.nn.gelu approximate=True)
            float inner = 0.7978845608028654f * (a + 0.044715f * a * a * a);
            float e  = __expf(2.0f * inner);
            float th = 1.0f - 2.0f / (e + 1.0f);
            float g  = 0.5f * a * (1.0f + th);
            int p = p0 - 1 + pi, c = c0 - 1 + pj;
            bool in_img = (p >= 0) & (p < P) & (c >= 0) & (c < cols);
            hs[ch][px] = in_img ? g : 0.0f;
        }
        __syncthreads();

        // conv2: 64 outputs, 4 threads/output (16 ch each) + shuffle reduce
        {
            const int pixel = tid >> 2, part = tid & 3;
            const int pi = pixel >> 3, pj = pixel & 7;
            const int base = pi * 10 + pj;
            float s = 0.f;
            for (int ch = part * 16; ch < part * 16 + 16; ++ch) {
                const float* w  = &w2s[ch * 9];
                const float* hr = &hs[ch][base];
                s = fmaf(w[0], hr[0],  s);
                s = fmaf(w[1], hr[1],  s);
                s = fmaf(w[2], hr[2],  s);
                s = fmaf(w[3], hr[10], s);
                s = fmaf(w[4], hr[11], s);
                s = fmaf(w[5], hr[12], s);
                s = fmaf(w[6], hr[20], s);
                s = fmaf(w[7], hr[21], s);
                s = fmaf(w[8], hr[22], s);
            }
            s += __shfl_down(s, 1);
            s += __shfl_down(s, 2);
            if (part == 0) {
                int p = p0 + pi, c = c0 + pj;
                if (p < P && c < cols) {
                    int t = c * P + p;
                    if (t < T_LEN) yout[b * T_LEN + t] = wgt * (s + bias2);
                }
            }
        }
    }
}

// ---------------------------------------------------------------------------
// Kernel 4: out[b][h] = sum_t (y0+y1)[b][t] * head_w[h][t] + head_b[h]
// ---------------------------------------------------------------------------
__global__ __launch_bounds__(256) void head_gemm_kernel(
    const float* __restrict__ ws, const float* __restrict__ hw,
    const float* __restrict__ hb, float* __restrict__ out)
{
    const float* y0 = ws + WS_Y0;
    const float* y1 = ws + WS_Y1;
    const int b0 = blockIdx.x * 16, h0 = blockIdx.y * 16;
    __shared__ float As[16][33];
    __shared__ float Bs[16][33];
    const int tid = threadIdx.x;
    const int i = tid >> 4;   // batch row
    const int j = tid & 15;   // head col
    float acc = 0.f;
    for (int k0 = 0; k0 < T_LEN; k0 += 32) {
        #pragma unroll
        for (int e = tid; e < 512; e += 256) {
            int r = e >> 5, kk = e & 31;
            int src = (b0 + r) * T_LEN + k0 + kk;
            As[r][kk] = y0[src] + y1[src];
            Bs[r][kk] = hw[(h0 + r) * T_LEN + k0 + kk];
        }
        __syncthreads();
        #pragma unroll
        for (int kk = 0; kk < 32; ++kk) acc = fmaf(As[i][kk], Bs[j][kk], acc);
        __syncthreads();
    }
    out[(b0 + i) * HORIZON + h0 + j] = acc + hb[h0 + j];
}

// ---------------------------------------------------------------------------
extern "C" void kernel_launch(void* const* d_in, const int* in_sizes, int n_in,
                              void* d_out, int out_size, void* d_ws, size_t ws_size,
                              hipStream_t stream) {
    const float* x   = (const float*)d_in[0];
    const float* c1w = (const float*)d_in[1];
    const float* c1b = (const float*)d_in[2];
    const float* c2w = (const float*)d_in[3];
    const float* c2b = (const float*)d_in[4];
    const float* hw  = (const float*)d_in[5];
    const float* hb  = (const float*)d_in[6];
    float* out = (float*)d_out;
    float* ws  = (float*)d_ws;

    float* amp = ws + WS_AMP;
    int*   mi  = (int*)(ws + WS_META);
    float* mf  = ws + WS_META;

    dft_amp_kernel<<<N_FREQ / KPB, 256, 0, stream>>>(x, amp);
    topk_meta_kernel<<<1, 256, 0, stream>>>(amp, mi, mf);
    conv_unit_kernel<<<dim3(4096, 2), 256, 0, stream>>>(x, c1w, c1b, c2w, c2b, mi, mf, ws);
    head_gemm_kernel<<<dim3(NB / 16, HORIZON / 16), 256, 0, stream>>>(ws, hw, hb, out);
}

// Round 2
// 538.756 us; speedup vs baseline: 4.2938x; 4.2938x over previous
//
#include <hip/hip_runtime.h>
#include <math.h>

#define T_LEN   2048
#define NB      256
#define N_FREQ  1024
#define DMODEL  64
#define HORIZON 720

// ws layout in floats. amp4 (4x1024 partials) aliases the start of Y0 —
// consumed by topk before conv overwrites Y0.
#define WS_META 0
#define WS_Y0   64
#define WS_Y1   (64 + NB * T_LEN)

#define KPB 4          // frequencies per block in DFT kernel
#define PMAX_FAST 191  // fast conv path handles P <= this; tile kernel covers rest
#define CHUNK 256      // outputs per block in fast conv
#define HSTRIDE 643    // >= HN_max(640) + zero slot
#define ZSLOT  642

// ---------------------------------------------------------------------------
// Kernel 1: direct DFT amplitude, batch-quarter partials. grid (256, 4).
// amp4[bq*1024 + (k-1)] = sum_{b in quarter} |X_b(k)| / 256
// ---------------------------------------------------------------------------
__global__ __launch_bounds__(256) void dft_amp_kernel(const float* __restrict__ x,
                                                      float* __restrict__ amp4) {
    __shared__ float stab[2048];
    __shared__ float rew[4][KPB][64];
    __shared__ float imw[4][KPB][64];
    const int tid = threadIdx.x;
    for (int m = tid; m < 2048; m += 256)
        stab[m] = (float)sin((double)m * 3.0679615757712823e-3);  // 2*pi/2048
    __syncthreads();

    const int wave = tid >> 6, lane = tid & 63;
    const int kbase = blockIdx.x * KPB + 1;
    const int bq = blockIdx.y;

    float cr[KPB][8], ci[KPB][8];
    #pragma unroll
    for (int kk = 0; kk < KPB; ++kk) {
        int k = kbase + kk;
        #pragma unroll
        for (int it = 0; it < 8; ++it) {
            int t = wave * 512 + it * 64 + lane;
            int m = (k * t) & 2047;
            cr[kk][it] = stab[(m + 512) & 2047];
            ci[kk][it] = stab[m];
        }
    }

    const float* xb = x + (bq * 64) * T_LEN + wave * 512 + lane;
    float v[8];
    #pragma unroll
    for (int it = 0; it < 8; ++it) v[it] = xb[it * 64];

    for (int ib = 0; ib < 64; ++ib) {
        float vn[8];
        if (ib < 63) {
            const float* xn = xb + (ib + 1) * T_LEN;
            #pragma unroll
            for (int it = 0; it < 8; ++it) vn[it] = xn[it * 64];
        }
        #pragma unroll
        for (int kk = 0; kk < KPB; ++kk) {
            float re = 0.f, im = 0.f;
            #pragma unroll
            for (int it = 0; it < 8; ++it) {
                re = fmaf(v[it], cr[kk][it], re);
                im = fmaf(v[it], ci[kk][it], im);
            }
            #pragma unroll
            for (int off = 32; off > 0; off >>= 1) {
                re += __shfl_xor(re, off);
                im += __shfl_xor(im, off);
            }
            if (lane == 0) { rew[wave][kk][ib] = re; imw[wave][kk][ib] = im; }
        }
        #pragma unroll
        for (int it = 0; it < 8; ++it) v[it] = vn[it];
    }
    __syncthreads();

    {   // tid -> (kk = tid>>6 == its own wave, bb = tid&63)
        int kk = tid >> 6, bb = tid & 63;
        float re = rew[0][kk][bb] + rew[1][kk][bb] + rew[2][kk][bb] + rew[3][kk][bb];
        float im = imw[0][kk][bb] + imw[1][kk][bb] + imw[2][kk][bb] + imw[3][kk][bb];
        float mag = sqrtf(re * re + im * im) * (1.0f / 256.0f);
        #pragma unroll
        for (int off = 32; off > 0; off >>= 1) mag += __shfl_xor(mag, off);
        if (bb == 0) amp4[bq * N_FREQ + (kbase + kk - 1)] = mag;
    }
}

// ---------------------------------------------------------------------------
// Kernel 2: top-2 over summed quarters, derive periods + softmax weights
// ---------------------------------------------------------------------------
__global__ void topk_meta_kernel(const float* __restrict__ amp4,
                                 int* __restrict__ mi, float* __restrict__ mf) {
    __shared__ float sv[256];
    __shared__ int   si[256];
    __shared__ float bpv[2];
    __shared__ int   bpi[2];
    const int tid = threadIdx.x;
    for (int pass = 0; pass < 2; ++pass) {
        int excl = (pass == 1) ? bpi[0] : -1;
        float bv = -1e30f; int bi = 1 << 30;
        for (int j = tid; j < N_FREQ; j += 256) {
            if (j == excl) continue;
            float v = amp4[j] + amp4[N_FREQ + j] + amp4[2 * N_FREQ + j] + amp4[3 * N_FREQ + j];
            if (v > bv || (v == bv && j < bi)) { bv = v; bi = j; }
        }
        sv[tid] = bv; si[tid] = bi;
        __syncthreads();
        for (int s = 128; s > 0; s >>= 1) {
            if (tid < s) {
                if (sv[tid + s] > sv[tid] ||
                    (sv[tid + s] == sv[tid] && si[tid + s] < si[tid])) {
                    sv[tid] = sv[tid + s]; si[tid] = si[tid + s];
                }
            }
            __syncthreads();
        }
        if (tid == 0) { bpv[pass] = sv[0]; bpi[pass] = si[0]; }
        __syncthreads();
    }
    if (tid == 0) {
        float v1 = bpv[0], v2 = bpv[1];
        int f1 = bpi[0] + 1, f2 = bpi[1] + 1;
        int P1 = (int)llround(2048.0 / (double)f1); if (P1 < 1) P1 = 1;
        int P2 = (int)llround(2048.0 / (double)f2); if (P2 < 1) P2 = 1;
        mi[0] = P1; mi[1] = (T_LEN + P1 - 1) / P1;
        mi[2] = P2; mi[3] = (T_LEN + P2 - 1) / P2;
        float mx = fmaxf(v1, v2);
        float e1 = expf(v1 - mx), e2 = expf(v2 - mx);
        float inv = 1.0f / (e1 + e2);
        mf[4] = e1 * inv; mf[5] = e2 * inv;
    }
}

// ---------------------------------------------------------------------------
// Kernel 3 (fast path, P <= PMAX_FAST): 1D-stencil formulation.
// Pixel (p,c) = x[c*P+p] => conv taps at t + {0,±1,±P,±(P±1)} with masks from
// (t mod P, t div P). Block = 256 contiguous outputs of one batch.
// h staged per 16-channel group in LDS as float4 rows; invalid conv2 taps
// read a dedicated zero slot via precomputed indices.
// ---------------------------------------------------------------------------
__global__ __launch_bounds__(256) void conv_fast_kernel(
    const float* __restrict__ x,
    const float* __restrict__ w1, const float* __restrict__ b1,
    const float* __restrict__ w2, const float* __restrict__ b2,
    const int* __restrict__ mi, const float* __restrict__ mf,
    float* __restrict__ ws)
{
    const int per  = blockIdx.y;
    const int P    = mi[per * 2 + 0];
    const int cols = mi[per * 2 + 1];
    if (P > PMAX_FAST) return;
    const float wgt = mf[4 + per];
    float* yout = ws + (per == 0 ? WS_Y0 : WS_Y1);

    __shared__ float  xs[1026];
    __shared__ float4 hs4[4][HSTRIDE];

    const int tid = threadIdx.x;
    const int b   = blockIdx.x >> 3;
    const int t0  = (blockIdx.x & 7) * CHUNK;
    const int U0  = t0 - (P + 1);            // first h position
    const int HN  = CHUNK + 2 * P + 2;       // h positions incl. halo (<= 640)
    const int X0  = t0 - (2 * P + 2);        // first x stage position
    const int XN  = CHUNK + 4 * P + 4;       // <= 1024

    for (int j = tid; j < XN; j += 256) {
        int t = X0 + j;
        xs[j] = (t >= 0 && t < T_LEN) ? x[b * T_LEN + t] : 0.f;
    }
    if (tid < 4) hs4[tid][ZSLOT] = make_float4(0.f, 0.f, 0.f, 0.f);

    // per-output tap indices (t = t0 + tid, always < T_LEN)
    const int t = t0 + tid;
    const int c = t / P;
    const int p = t - c * P;
    const int iout = tid + (P + 1);
    {
        // nothing
    }
    const bool rm = p > 0, rp = p < P - 1, cm = c > 0, cp = (c + 1) < cols;
    int idx[9];
    idx[0] = (rm && cm) ? iout - P - 1 : ZSLOT;
    idx[1] = rm         ? iout - 1     : ZSLOT;
    idx[2] = (rm && cp) ? iout + P - 1 : ZSLOT;
    idx[3] = cm         ? iout - P     : ZSLOT;
    idx[4] =              iout;
    idx[5] = cp         ? iout + P     : ZSLOT;
    idx[6] = (rp && cm) ? iout - P + 1 : ZSLOT;
    idx[7] = rp         ? iout + 1     : ZSLOT;
    idx[8] = (rp && cp) ? iout + P + 1 : ZSLOT;

    // per-position conv1 masks (group-invariant); <=3 positions/thread
    auto posmask = [&](int i) -> int {
        int u = U0 + i;
        int uu = u < 0 ? 0 : u;
        int cc = uu / P;
        int pp = uu - cc * P;
        int rm1 = pp > 0, rp1 = pp < P - 1, cm1 = cc > 0, cp1 = (cc + 1) < cols;
        return (rm1 & cm1) | (rm1 << 1) | ((rm1 & cp1) << 2) | (cm1 << 3) |
               (1 << 4) | (cp1 << 5) | ((rp1 & cm1) << 6) | (rp1 << 7) |
               ((rp1 & cp1) << 8);
    };
    const bool has1 = (tid + 256) < HN;
    const bool has2 = (tid + 512) < HN;
    const int mb0 = posmask(tid);
    const int mb1 = has1 ? posmask(tid + 256) : 0;
    const int mb2 = has2 ? posmask(tid + 512) : 0;

    auto do_pos = [&](int i, int mb, int g) {
        const int ibase = i + P + 1;   // xs index of tap center
        float xv[9];
        xv[0] = (mb & 1)   ? xs[ibase - P - 1] : 0.f;
        xv[1] = (mb & 2)   ? xs[ibase - 1]     : 0.f;
        xv[2] = (mb & 4)   ? xs[ibase + P - 1] : 0.f;
        xv[3] = (mb & 8)   ? xs[ibase - P]     : 0.f;
        xv[4] =              xs[ibase];
        xv[5] = (mb & 32)  ? xs[ibase + P]     : 0.f;
        xv[6] = (mb & 64)  ? xs[ibase - P + 1] : 0.f;
        xv[7] = (mb & 128) ? xs[ibase + 1]     : 0.f;
        xv[8] = (mb & 256) ? xs[ibase + P + 1] : 0.f;
        #pragma unroll
        for (int r = 0; r < 4; ++r) {
            float4 hv;
            float* hvp = (float*)&hv;
            #pragma unroll
            for (int e = 0; e < 4; ++e) {
                int ch = g * 16 + r * 4 + e;
                const float* wr = w1 + ch * 9;
                float a = b1[ch];
                #pragma unroll
                for (int k = 0; k < 9; ++k) a = fmaf(wr[k], xv[k], a);
                float inner = 0.7978845608028654f * (a + 0.044715f * a * a * a);
                float eo = __expf(2.0f * inner);
                float th = 1.0f - 2.0f / (eo + 1.0f);
                hvp[e] = 0.5f * a * (1.0f + th);
            }
            hs4[r][i] = hv;
        }
    };

    float s = 0.f;
    for (int g = 0; g < 4; ++g) {
        __syncthreads();   // g=0: xs + zero slot ready; g>0: prev conv2 done
        do_pos(tid, mb0, g);
        if (has1) do_pos(tid + 256, mb1, g);
        if (has2) do_pos(tid + 512, mb2, g);
        __syncthreads();
        #pragma unroll
        for (int r = 0; r < 4; ++r) {
            const float* wr = w2 + (g * 16 + r * 4) * 9;
            #pragma unroll
            for (int k = 0; k < 9; ++k) {
                float4 hv = hs4[r][idx[k]];
                s = fmaf(wr[k],      hv.x, s);
                s = fmaf(wr[9 + k],  hv.y, s);
                s = fmaf(wr[18 + k], hv.z, s);
                s = fmaf(wr[27 + k], hv.w, s);
            }
        }
    }
    yout[b * T_LEN + t] = wgt * (s + b2[0]);
}

// ---------------------------------------------------------------------------
// Kernel 3b (fallback, P > PMAX_FAST): proven 2D tile version, grid-stride.
// ---------------------------------------------------------------------------
__global__ __launch_bounds__(256) void conv_unit_kernel(
    const float* __restrict__ x,
    const float* __restrict__ w1, const float* __restrict__ b1,
    const float* __restrict__ w2, const float* __restrict__ b2,
    const int* __restrict__ mi, const float* __restrict__ mf,
    float* __restrict__ ws)
{
    const int per   = blockIdx.y;
    const int P     = mi[per * 2 + 0];
    const int cols  = mi[per * 2 + 1];
    if (P <= PMAX_FAST) return;      // fast path handled it
    const float wgt = mf[4 + per];
    float* yout = ws + (per == 0 ? WS_Y0 : WS_Y1);

    __shared__ float w1s[DMODEL * 9];
    __shared__ float w2s[DMODEL * 9];
    __shared__ float b1s[DMODEL];
    __shared__ float xs[12][13];
    __shared__ float hs[DMODEL][101];

    const int tid = threadIdx.x;
    for (int i = tid; i < DMODEL * 9; i += 256) { w1s[i] = w1[i]; w2s[i] = w2[i]; }
    if (tid < DMODEL) b1s[tid] = b1[tid];
    const float bias2 = b2[0];

    const int tp = (P + 7) >> 3;
    const int tc = (cols + 7) >> 3;
    const int tiles_img = tp * tc;
    const int total = tiles_img * NB;

    for (int tile = blockIdx.x; tile < total; tile += gridDim.x) {
        const int b   = tile / tiles_img;
        const int ti  = tile - b * tiles_img;
        const int tpi = ti / tc;
        const int tci = ti - tpi * tc;
        const int p0 = tpi * 8, c0 = tci * 8;

        __syncthreads();
        if (tid < 144) {
            int i = tid / 12, j = tid - (tid / 12) * 12;
            int pp = p0 - 2 + i, cc = c0 - 2 + j;
            float v = 0.f;
            if (pp >= 0 && pp < P && cc >= 0 && cc < cols) {
                int t = cc * P + pp;
                if (t < T_LEN) v = x[b * T_LEN + t];
            }
            xs[i][j] = v;
        }
        __syncthreads();

        #pragma unroll
        for (int it = 0; it < 25; ++it) {
            int idx = it * 256 + tid;
            int ch = idx / 100;
            int px = idx - ch * 100;
            int pi = px / 10;
            int pj = px - pi * 10;
            const float* w = &w1s[ch * 9];
            float a = b1s[ch];
            a = fmaf(w[0], xs[pi    ][pj    ], a);
            a = fmaf(w[1], xs[pi    ][pj + 1], a);
            a = fmaf(w[2], xs[pi    ][pj + 2], a);
            a = fmaf(w[3], xs[pi + 1][pj    ], a);
            a = fmaf(w[4], xs[pi + 1][pj + 1], a);
            a = fmaf(w[5], xs[pi + 1][pj + 2], a);
            a = fmaf(w[6], xs[pi + 2][pj    ], a);
            a = fmaf(w[7], xs[pi + 2][pj + 1], a);
            a = fmaf(w[8], xs[pi + 2][pj + 2], a);
            float inner = 0.7978845608028654f * (a + 0.044715f * a * a * a);
            float e  = __expf(2.0f * inner);
            float th = 1.0f - 2.0f / (e + 1.0f);
            float g  = 0.5f * a * (1.0f + th);
            int pp = p0 - 1 + pi, cc = c0 - 1 + pj;
            bool in_img = (pp >= 0) & (pp < P) & (cc >= 0) & (cc < cols);
            hs[ch][px] = in_img ? g : 0.0f;
        }
        __syncthreads();

        {
            const int pixel = tid >> 2, part = tid & 3;
            const int pi = pixel >> 3, pj = pixel & 7;
            const int base = pi * 10 + pj;
            float s = 0.f;
            for (int ch = part * 16; ch < part * 16 + 16; ++ch) {
                const float* w  = &w2s[ch * 9];
                const float* hr = &hs[ch][base];
                s = fmaf(w[0], hr[0],  s);
                s = fmaf(w[1], hr[1],  s);
                s = fmaf(w[2], hr[2],  s);
                s = fmaf(w[3], hr[10], s);
                s = fmaf(w[4], hr[11], s);
                s = fmaf(w[5], hr[12], s);
                s = fmaf(w[6], hr[20], s);
                s = fmaf(w[7], hr[21], s);
                s = fmaf(w[8], hr[22], s);
            }
            s += __shfl_down(s, 1);
            s += __shfl_down(s, 2);
            if (part == 0) {
                int pp = p0 + pi, cc = c0 + pj;
                if (pp < P && cc < cols) {
                    int t = cc * P + pp;
                    if (t < T_LEN) yout[b * T_LEN + t] = wgt * (s + bias2);
                }
            }
        }
    }
}

// ---------------------------------------------------------------------------
// Kernel 4: out = (y0+y1) @ head_w^T + head_b. 32x32 tiles, 2x2 per thread.
// ---------------------------------------------------------------------------
__global__ __launch_bounds__(256) void head_gemm_kernel(
    const float* __restrict__ ws, const float* __restrict__ hw,
    const float* __restrict__ hb, float* __restrict__ out)
{
    const float* y0 = ws + WS_Y0;
    const float* y1 = ws + WS_Y1;
    const int b0 = blockIdx.x * 32, h0 = blockIdx.y * 32;
    __shared__ float As[32][33];
    __shared__ float Bs[32][33];
    const int tid = threadIdx.x;
    const int tx = tid & 15, ty = tid >> 4;
    const int i0 = ty * 2, j0 = tx * 2;
    float a00 = 0.f, a01 = 0.f, a10 = 0.f, a11 = 0.f;
    for (int k0 = 0; k0 < T_LEN; k0 += 32) {
        #pragma unroll
        for (int e = tid; e < 1024; e += 256) {
            int r = e >> 5, kk = e & 31;
            int src = (b0 + r) * T_LEN + k0 + kk;
            As[r][kk] = y0[src] + y1[src];
            int hrow = h0 + r;
            Bs[r][kk] = (hrow < HORIZON) ? hw[hrow * T_LEN + k0 + kk] : 0.f;
        }
        __syncthreads();
        #pragma unroll
        for (int kk = 0; kk < 32; ++kk) {
            float av0 = As[i0][kk], av1 = As[i0 + 1][kk];
            float bv0 = Bs[j0][kk], bv1 = Bs[j0 + 1][kk];
            a00 = fmaf(av0, bv0, a00); a01 = fmaf(av0, bv1, a01);
            a10 = fmaf(av1, bv0, a10); a11 = fmaf(av1, bv1, a11);
        }
        __syncthreads();
    }
    const int bi = b0 + i0, hj = h0 + j0;
    if (hj < HORIZON) {
        float bb = hb[hj];
        out[bi * HORIZON + hj]       = a00 + bb;
        out[(bi + 1) * HORIZON + hj] = a10 + bb;
    }
    if (hj + 1 < HORIZON) {
        float bb = hb[hj + 1];
        out[bi * HORIZON + hj + 1]       = a01 + bb;
        out[(bi + 1) * HORIZON + hj + 1] = a11 + bb;
    }
}

// ---------------------------------------------------------------------------
extern "C" void kernel_launch(void* const* d_in, const int* in_sizes, int n_in,
                              void* d_out, int out_size, void* d_ws, size_t ws_size,
                              hipStream_t stream) {
    const float* x   = (const float*)d_in[0];
    const float* c1w = (const float*)d_in[1];
    const float* c1b = (const float*)d_in[2];
    const float* c2w = (const float*)d_in[3];
    const float* c2b = (const float*)d_in[4];
    const float* hw  = (const float*)d_in[5];
    const float* hb  = (const float*)d_in[6];
    float* out = (float*)d_out;
    float* ws  = (float*)d_ws;

    float* amp4 = ws + WS_Y0;            // aliases Y0; consumed before conv
    int*   mi   = (int*)(ws + WS_META);
    float* mf   = ws + WS_META;

    dft_amp_kernel<<<dim3(N_FREQ / KPB, 4), 256, 0, stream>>>(x, amp4);
    topk_meta_kernel<<<1, 256, 0, stream>>>(amp4, mi, mf);
    conv_fast_kernel<<<dim3(NB * 8, 2), 256, 0, stream>>>(x, c1w, c1b, c2w, c2b, mi, mf, ws);
    conv_unit_kernel<<<dim3(1024, 2), 256, 0, stream>>>(x, c1w, c1b, c2w, c2b, mi, mf, ws);
    head_gemm_kernel<<<dim3(NB / 32, (HORIZON + 31) / 32), 256, 0, stream>>>(ws, hw, hb, out);
}

// Round 3
// 259.827 us; speedup vs baseline: 8.9032x; 2.0735x over previous
//
#include <hip/hip_runtime.h>
#include <math.h>

#define T_LEN   2048
#define NB      256
#define N_FREQ  1024
#define DMODEL  64
#define HORIZON 720

// ws layout in floats
#define WS_META 0                     // mi[0..3] ints, mf[4..5] floats
#define WS_AMP  64                    // 1024 floats, zeroed by memset each launch
#define WS_Y0   2048
#define WS_Y1   (2048 + NB * T_LEN)

#define PMAX_FAST 191  // fast conv path handles P <= this; tile kernel covers rest
#define CHUNK 256      // outputs per block in fast conv
#define HSTRIDE 643    // >= HN_max(640) + zero slot
#define ZSLOT  642

// ---------------------------------------------------------------------------
// Kernel 1: per-batch 2048-pt complex FFT (radix-2 Stockham, LDS ping-pong),
// then atomicAdd |X(k)|/256 into amp[k-1], k=1..1024. One batch per block.
// Twiddle table tw[m] = exp(-2*pi*i*m/2048) matches numpy rfft sign.
// ---------------------------------------------------------------------------
__global__ __launch_bounds__(256) void fft_amp_kernel(const float* __restrict__ x,
                                                      float* __restrict__ amp) {
    __shared__ float2 buf0[2048];
    __shared__ float2 buf1[2048];
    __shared__ float2 tw[1024];
    const int tid = threadIdx.x;
    const int b = blockIdx.x;

    #pragma unroll
    for (int u = 0; u < 4; ++u) {
        int m = tid + u * 256;
        float s, c;
        __sincosf((float)m * 3.0679615757712823e-3f, &s, &c);  // 2*pi/2048
        tw[m] = make_float2(c, -s);
    }
    const float* xb = x + b * T_LEN;
    #pragma unroll
    for (int u = 0; u < 8; ++u) {
        int i = tid + u * 256;
        buf0[i] = make_float2(xb[i], 0.f);
    }
    __syncthreads();

    float2* src = buf0;
    float2* dst = buf1;
    for (int s = 0; s < 11; ++s) {
        const int Ns = 1 << s;
        #pragma unroll
        for (int u = 0; u < 4; ++u) {
            int j = tid + u * 256;          // 0..1023
            int q = j & (Ns - 1);
            int base = ((j >> s) << (s + 1)) + q;
            float2 a  = src[j];
            float2 bb = src[j + 1024];
            float2 w  = tw[q << (10 - s)];
            float2 t  = make_float2(w.x * bb.x - w.y * bb.y,
                                    w.x * bb.y + w.y * bb.x);
            dst[base]      = make_float2(a.x + t.x, a.y + t.y);
            dst[base + Ns] = make_float2(a.x - t.x, a.y - t.y);
        }
        __syncthreads();
        float2* tmp = src; src = dst; dst = tmp;
    }
    // result (natural order) is in src
    #pragma unroll
    for (int u = 0; u < 4; ++u) {
        int k = tid + u * 256 + 1;          // 1..1024
        float2 X = src[k];
        atomicAdd(amp + (k - 1), sqrtf(X.x * X.x + X.y * X.y) * (1.0f / 256.0f));
    }
}

// ---------------------------------------------------------------------------
// Kernel 2: top-2 of amp, derive periods + softmax weights
// ---------------------------------------------------------------------------
__global__ void topk_meta_kernel(const float* __restrict__ amp,
                                 int* __restrict__ mi, float* __restrict__ mf) {
    __shared__ float sv[256];
    __shared__ int   si[256];
    __shared__ float bpv[2];
    __shared__ int   bpi[2];
    const int tid = threadIdx.x;
    for (int pass = 0; pass < 2; ++pass) {
        int excl = (pass == 1) ? bpi[0] : -1;
        float bv = -1e30f; int bi = 1 << 30;
        for (int j = tid; j < N_FREQ; j += 256) {
            if (j == excl) continue;
            float v = amp[j];
            if (v > bv || (v == bv && j < bi)) { bv = v; bi = j; }
        }
        sv[tid] = bv; si[tid] = bi;
        __syncthreads();
        for (int s = 128; s > 0; s >>= 1) {
            if (tid < s) {
                if (sv[tid + s] > sv[tid] ||
                    (sv[tid + s] == sv[tid] && si[tid + s] < si[tid])) {
                    sv[tid] = sv[tid + s]; si[tid] = si[tid + s];
                }
            }
            __syncthreads();
        }
        if (tid == 0) { bpv[pass] = sv[0]; bpi[pass] = si[0]; }
        __syncthreads();
    }
    if (tid == 0) {
        float v1 = bpv[0], v2 = bpv[1];
        int f1 = bpi[0] + 1, f2 = bpi[1] + 1;
        int P1 = (int)llround(2048.0 / (double)f1); if (P1 < 1) P1 = 1;
        int P2 = (int)llround(2048.0 / (double)f2); if (P2 < 1) P2 = 1;
        mi[0] = P1; mi[1] = (T_LEN + P1 - 1) / P1;
        mi[2] = P2; mi[3] = (T_LEN + P2 - 1) / P2;
        float mx = fmaxf(v1, v2);
        float e1 = expf(v1 - mx), e2 = expf(v2 - mx);
        float inv = 1.0f / (e1 + e2);
        mf[4] = e1 * inv; mf[5] = e2 * inv;
    }
}

// ---------------------------------------------------------------------------
// Kernel 3 (fast path, P <= PMAX_FAST): 1D-stencil conv unit (unchanged)
// ---------------------------------------------------------------------------
__global__ __launch_bounds__(256) void conv_fast_kernel(
    const float* __restrict__ x,
    const float* __restrict__ w1, const float* __restrict__ b1,
    const float* __restrict__ w2, const float* __restrict__ b2,
    const int* __restrict__ mi, const float* __restrict__ mf,
    float* __restrict__ ws)
{
    const int per  = blockIdx.y;
    const int P    = mi[per * 2 + 0];
    const int cols = mi[per * 2 + 1];
    if (P > PMAX_FAST) return;
    const float wgt = mf[4 + per];
    float* yout = ws + (per == 0 ? WS_Y0 : WS_Y1);

    __shared__ float  xs[1026];
    __shared__ float4 hs4[4][HSTRIDE];

    const int tid = threadIdx.x;
    const int b   = blockIdx.x >> 3;
    const int t0  = (blockIdx.x & 7) * CHUNK;
    const int U0  = t0 - (P + 1);
    const int HN  = CHUNK + 2 * P + 2;
    const int X0  = t0 - (2 * P + 2);
    const int XN  = CHUNK + 4 * P + 4;

    for (int j = tid; j < XN; j += 256) {
        int t = X0 + j;
        xs[j] = (t >= 0 && t < T_LEN) ? x[b * T_LEN + t] : 0.f;
    }
    if (tid < 4) hs4[tid][ZSLOT] = make_float4(0.f, 0.f, 0.f, 0.f);

    const int t = t0 + tid;
    const int c = t / P;
    const int p = t - c * P;
    const int iout = tid + (P + 1);
    const bool rm = p > 0, rp = p < P - 1, cm = c > 0, cp = (c + 1) < cols;
    int idx[9];
    idx[0] = (rm && cm) ? iout - P - 1 : ZSLOT;
    idx[1] = rm         ? iout - 1     : ZSLOT;
    idx[2] = (rm && cp) ? iout + P - 1 : ZSLOT;
    idx[3] = cm         ? iout - P     : ZSLOT;
    idx[4] =              iout;
    idx[5] = cp         ? iout + P     : ZSLOT;
    idx[6] = (rp && cm) ? iout - P + 1 : ZSLOT;
    idx[7] = rp         ? iout + 1     : ZSLOT;
    idx[8] = (rp && cp) ? iout + P + 1 : ZSLOT;

    auto posmask = [&](int i) -> int {
        int u = U0 + i;
        int uu = u < 0 ? 0 : u;
        int cc = uu / P;
        int pp = uu - cc * P;
        int rm1 = pp > 0, rp1 = pp < P - 1, cm1 = cc > 0, cp1 = (cc + 1) < cols;
        return (rm1 & cm1) | (rm1 << 1) | ((rm1 & cp1) << 2) | (cm1 << 3) |
               (1 << 4) | (cp1 << 5) | ((rp1 & cm1) << 6) | (rp1 << 7) |
               ((rp1 & cp1) << 8);
    };
    const bool has1 = (tid + 256) < HN;
    const bool has2 = (tid + 512) < HN;
    const int mb0 = posmask(tid);
    const int mb1 = has1 ? posmask(tid + 256) : 0;
    const int mb2 = has2 ? posmask(tid + 512) : 0;

    auto do_pos = [&](int i, int mb, int g) {
        const int ibase = i + P + 1;
        float xv[9];
        xv[0] = (mb & 1)   ? xs[ibase - P - 1] : 0.f;
        xv[1] = (mb & 2)   ? xs[ibase - 1]     : 0.f;
        xv[2] = (mb & 4)   ? xs[ibase + P - 1] : 0.f;
        xv[3] = (mb & 8)   ? xs[ibase - P]     : 0.f;
        xv[4] =              xs[ibase];
        xv[5] = (mb & 32)  ? xs[ibase + P]     : 0.f;
        xv[6] = (mb & 64)  ? xs[ibase - P + 1] : 0.f;
        xv[7] = (mb & 128) ? xs[ibase + 1]     : 0.f;
        xv[8] = (mb & 256) ? xs[ibase + P + 1] : 0.f;
        #pragma unroll
        for (int r = 0; r < 4; ++r) {
            float4 hv;
            float* hvp = (float*)&hv;
            #pragma unroll
            for (int e = 0; e < 4; ++e) {
                int ch = g * 16 + r * 4 + e;
                const float* wr = w1 + ch * 9;
                float a = b1[ch];
                #pragma unroll
                for (int k = 0; k < 9; ++k) a = fmaf(wr[k], xv[k], a);
                float inner = 0.7978845608028654f * (a + 0.044715f * a * a * a);
                float eo = __expf(2.0f * inner);
                float th = 1.0f - 2.0f / (eo + 1.0f);
                hvp[e] = 0.5f * a * (1.0f + th);
            }
            hs4[r][i] = hv;
        }
    };

    float s = 0.f;
    for (int g = 0; g < 4; ++g) {
        __syncthreads();
        do_pos(tid, mb0, g);
        if (has1) do_pos(tid + 256, mb1, g);
        if (has2) do_pos(tid + 512, mb2, g);
        __syncthreads();
        #pragma unroll
        for (int r = 0; r < 4; ++r) {
            const float* wr = w2 + (g * 16 + r * 4) * 9;
            #pragma unroll
            for (int k = 0; k < 9; ++k) {
                float4 hv = hs4[r][idx[k]];
                s = fmaf(wr[k],      hv.x, s);
                s = fmaf(wr[9 + k],  hv.y, s);
                s = fmaf(wr[18 + k], hv.z, s);
                s = fmaf(wr[27 + k], hv.w, s);
            }
        }
    }
    yout[b * T_LEN + t] = wgt * (s + b2[0]);
}

// ---------------------------------------------------------------------------
// Kernel 3b (fallback, P > PMAX_FAST): 2D tile version, grid-stride
// ---------------------------------------------------------------------------
__global__ __launch_bounds__(256) void conv_unit_kernel(
    const float* __restrict__ x,
    const float* __restrict__ w1, const float* __restrict__ b1,
    const float* __restrict__ w2, const float* __restrict__ b2,
    const int* __restrict__ mi, const float* __restrict__ mf,
    float* __restrict__ ws)
{
    const int per   = blockIdx.y;
    const int P     = mi[per * 2 + 0];
    const int cols  = mi[per * 2 + 1];
    if (P <= PMAX_FAST) return;
    const float wgt = mf[4 + per];
    float* yout = ws + (per == 0 ? WS_Y0 : WS_Y1);

    __shared__ float w1s[DMODEL * 9];
    __shared__ float w2s[DMODEL * 9];
    __shared__ float b1s[DMODEL];
    __shared__ float xs[12][13];
    __shared__ float hs[DMODEL][101];

    const int tid = threadIdx.x;
    for (int i = tid; i < DMODEL * 9; i += 256) { w1s[i] = w1[i]; w2s[i] = w2[i]; }
    if (tid < DMODEL) b1s[tid] = b1[tid];
    const float bias2 = b2[0];

    const int tp = (P + 7) >> 3;
    const int tc = (cols + 7) >> 3;
    const int tiles_img = tp * tc;
    const int total = tiles_img * NB;

    for (int tile = blockIdx.x; tile < total; tile += gridDim.x) {
        const int b   = tile / tiles_img;
        const int ti  = tile - b * tiles_img;
        const int tpi = ti / tc;
        const int tci = ti - tpi * tc;
        const int p0 = tpi * 8, c0 = tci * 8;

        __syncthreads();
        if (tid < 144) {
            int i = tid / 12, j = tid - (tid / 12) * 12;
            int pp = p0 - 2 + i, cc = c0 - 2 + j;
            float v = 0.f;
            if (pp >= 0 && pp < P && cc >= 0 && cc < cols) {
                int t = cc * P + pp;
                if (t < T_LEN) v = x[b * T_LEN + t];
            }
            xs[i][j] = v;
        }
        __syncthreads();

        #pragma unroll
        for (int it = 0; it < 25; ++it) {
            int idx = it * 256 + tid;
            int ch = idx / 100;
            int px = idx - ch * 100;
            int pi = px / 10;
            int pj = px - pi * 10;
            const float* w = &w1s[ch * 9];
            float a = b1s[ch];
            a = fmaf(w[0], xs[pi    ][pj    ], a);
            a = fmaf(w[1], xs[pi    ][pj + 1], a);
            a = fmaf(w[2], xs[pi    ][pj + 2], a);
            a = fmaf(w[3], xs[pi + 1][pj    ], a);
            a = fmaf(w[4], xs[pi + 1][pj + 1], a);
            a = fmaf(w[5], xs[pi + 1][pj + 2], a);
            a = fmaf(w[6], xs[pi + 2][pj    ], a);
            a = fmaf(w[7], xs[pi + 2][pj + 1], a);
            a = fmaf(w[8], xs[pi + 2][pj + 2], a);
            float inner = 0.7978845608028654f * (a + 0.044715f * a * a * a);
            float e  = __expf(2.0f * inner);
            float th = 1.0f - 2.0f / (e + 1.0f);
            float g  = 0.5f * a * (1.0f + th);
            int pp = p0 - 1 + pi, cc = c0 - 1 + pj;
            bool in_img = (pp >= 0) & (pp < P) & (cc >= 0) & (cc < cols);
            hs[ch][px] = in_img ? g : 0.0f;
        }
        __syncthreads();

        {
            const int pixel = tid >> 2, part = tid & 3;
            const int pi = pixel >> 3, pj = pixel & 7;
            const int base = pi * 10 + pj;
            float s = 0.f;
            for (int ch = part * 16; ch < part * 16 + 16; ++ch) {
                const float* w  = &w2s[ch * 9];
                const float* hr = &hs[ch][base];
                s = fmaf(w[0], hr[0],  s);
                s = fmaf(w[1], hr[1],  s);
                s = fmaf(w[2], hr[2],  s);
                s = fmaf(w[3], hr[10], s);
                s = fmaf(w[4], hr[11], s);
                s = fmaf(w[5], hr[12], s);
                s = fmaf(w[6], hr[20], s);
                s = fmaf(w[7], hr[21], s);
                s = fmaf(w[8], hr[22], s);
            }
            s += __shfl_down(s, 1);
            s += __shfl_down(s, 2);
            if (part == 0) {
                int pp = p0 + pi, cc = c0 + pj;
                if (pp < P && cc < cols) {
                    int t = cc * P + pp;
                    if (t < T_LEN) yout[b * T_LEN + t] = wgt * (s + bias2);
                }
            }
        }
    }
}

// ---------------------------------------------------------------------------
// Kernel 4: split-K head GEMM. grid (8, 23, 8): 32x32 out tile, K-chunk 256.
// Partials atomicAdd'ed into out (zeroed by memset); z==0 adds bias.
// ---------------------------------------------------------------------------
__global__ __launch_bounds__(256) void head_gemm_kernel(
    const float* __restrict__ ws, const float* __restrict__ hw,
    const float* __restrict__ hb, float* __restrict__ out)
{
    const float* y0 = ws + WS_Y0;
    const float* y1 = ws + WS_Y1;
    const int b0 = blockIdx.x * 32, h0 = blockIdx.y * 32;
    const int kc0 = blockIdx.z * 256;
    __shared__ float As[32][33];
    __shared__ float Bs[32][33];
    const int tid = threadIdx.x;
    const int tx = tid & 15, ty = tid >> 4;
    const int i0 = ty * 2, j0 = tx * 2;
    float a00 = 0.f, a01 = 0.f, a10 = 0.f, a11 = 0.f;
    for (int k0 = kc0; k0 < kc0 + 256; k0 += 32) {
        #pragma unroll
        for (int e = tid; e < 1024; e += 256) {
            int r = e >> 5, kk = e & 31;
            int src = (b0 + r) * T_LEN + k0 + kk;
            As[r][kk] = y0[src] + y1[src];
            int hrow = h0 + r;
            Bs[r][kk] = (hrow < HORIZON) ? hw[hrow * T_LEN + k0 + kk] : 0.f;
        }
        __syncthreads();
        #pragma unroll
        for (int kk = 0; kk < 32; ++kk) {
            float av0 = As[i0][kk], av1 = As[i0 + 1][kk];
            float bv0 = Bs[j0][kk], bv1 = Bs[j0 + 1][kk];
            a00 = fmaf(av0, bv0, a00); a01 = fmaf(av0, bv1, a01);
            a10 = fmaf(av1, bv0, a10); a11 = fmaf(av1, bv1, a11);
        }
        __syncthreads();
    }
    const int bi = b0 + i0, hj = h0 + j0;
    if (blockIdx.z == 0) {
        if (hj < HORIZON)     { float bb = hb[hj];     a00 += bb; a10 += bb; }
        if (hj + 1 < HORIZON) { float bb = hb[hj + 1]; a01 += bb; a11 += bb; }
    }
    if (hj < HORIZON) {
        atomicAdd(&out[bi * HORIZON + hj], a00);
        atomicAdd(&out[(bi + 1) * HORIZON + hj], a10);
    }
    if (hj + 1 < HORIZON) {
        atomicAdd(&out[bi * HORIZON + hj + 1], a01);
        atomicAdd(&out[(bi + 1) * HORIZON + hj + 1], a11);
    }
}

// ---------------------------------------------------------------------------
extern "C" void kernel_launch(void* const* d_in, const int* in_sizes, int n_in,
                              void* d_out, int out_size, void* d_ws, size_t ws_size,
                              hipStream_t stream) {
    const float* x   = (const float*)d_in[0];
    const float* c1w = (const float*)d_in[1];
    const float* c1b = (const float*)d_in[2];
    const float* c2w = (const float*)d_in[3];
    const float* c2b = (const float*)d_in[4];
    const float* hw  = (const float*)d_in[5];
    const float* hb  = (const float*)d_in[6];
    float* out = (float*)d_out;
    float* ws  = (float*)d_ws;

    float* amp = ws + WS_AMP;
    int*   mi  = (int*)(ws + WS_META);
    float* mf  = ws + WS_META;

    hipMemsetAsync(amp, 0, N_FREQ * sizeof(float), stream);
    hipMemsetAsync(out, 0, (size_t)out_size * sizeof(float), stream);
    fft_amp_kernel<<<NB, 256, 0, stream>>>(x, amp);
    topk_meta_kernel<<<1, 256, 0, stream>>>(amp, mi, mf);
    conv_fast_kernel<<<dim3(NB * 8, 2), 256, 0, stream>>>(x, c1w, c1b, c2w, c2b, mi, mf, ws);
    conv_unit_kernel<<<dim3(1024, 2), 256, 0, stream>>>(x, c1w, c1b, c2w, c2b, mi, mf, ws);
    head_gemm_kernel<<<dim3(NB / 32, (HORIZON + 31) / 32, 8), 256, 0, stream>>>(ws, hw, hb, out);
}

// Round 4
// 237.092 us; speedup vs baseline: 9.7569x; 1.0959x over previous
//
#include <hip/hip_runtime.h>
#include <math.h>

#define T_LEN   2048
#define NB      256
#define N_FREQ  1024
#define DMODEL  64
#define HORIZON 720

// ws layout in floats
#define WS_META 0                     // mi[0..3] ints, mf[4..5] floats
#define WS_AMP  64                    // 1024 floats, zeroed by memset each launch
#define WS_Y0   2048
#define WS_Y1   (2048 + NB * T_LEN)

#define PMAX_FAST 191  // fast conv path handles P <= this; tile kernel covers rest
#define CHUNK   512    // outputs per block in fast conv (2 per thread)
#define HSTRIDE 899    // >= HN_max(898) + zero slot
#define ZSLOT   898

// cheap tanh-GELU: 0.5*a*(1+tanh(0.79788456*(a+0.044715 a^3))) == a*rcp(1+exp(z)),
// z = a*(c1 + c2*a^2), c1 = -2*0.79788456..., c2 = c1*0.044715
__device__ __forceinline__ float gelu_fast(float a) {
    float a2 = a * a;
    float z  = a * fmaf(-0.07135481627159498f, a2, -1.5957691216057308f);
    float e  = __expf(z);
    return a * __builtin_amdgcn_rcpf(1.0f + e);
}

// ---------------------------------------------------------------------------
// Kernel 1: per-batch 2048-pt complex FFT (radix-2 Stockham, LDS ping-pong),
// then atomicAdd |X(k)|/256 into amp[k-1], k=1..1024, with per-block address
// rotation to avoid 256-way atomic contention.
// ---------------------------------------------------------------------------
__global__ __launch_bounds__(256) void fft_amp_kernel(const float* __restrict__ x,
                                                      float* __restrict__ amp) {
    __shared__ float2 buf0[2048];
    __shared__ float2 buf1[2048];
    __shared__ float2 tw[1024];
    const int tid = threadIdx.x;
    const int b = blockIdx.x;

    #pragma unroll
    for (int u = 0; u < 4; ++u) {
        int m = tid + u * 256;
        float s, c;
        __sincosf((float)m * 3.0679615757712823e-3f, &s, &c);  // 2*pi/2048
        tw[m] = make_float2(c, -s);
    }
    const float* xb = x + b * T_LEN;
    #pragma unroll
    for (int u = 0; u < 8; ++u) {
        int i = tid + u * 256;
        buf0[i] = make_float2(xb[i], 0.f);
    }
    __syncthreads();

    float2* src = buf0;
    float2* dst = buf1;
    for (int s = 0; s < 11; ++s) {
        const int Ns = 1 << s;
        #pragma unroll
        for (int u = 0; u < 4; ++u) {
            int j = tid + u * 256;          // 0..1023
            int q = j & (Ns - 1);
            int base = ((j >> s) << (s + 1)) + q;
            float2 a  = src[j];
            float2 bb = src[j + 1024];
            float2 w  = tw[q << (10 - s)];
            float2 t  = make_float2(w.x * bb.x - w.y * bb.y,
                                    w.x * bb.y + w.y * bb.x);
            dst[base]      = make_float2(a.x + t.x, a.y + t.y);
            dst[base + Ns] = make_float2(a.x - t.x, a.y - t.y);
        }
        __syncthreads();
        float2* tmp = src; src = dst; dst = tmp;
    }
    // result (natural order) is in src; rotate write order per block
    const int rot = (b * 8) & 1023;
    #pragma unroll
    for (int u = 0; u < 4; ++u) {
        int kk = (tid + u * 256 + rot) & 1023;   // amp index, freq k = kk+1
        float2 X = src[kk + 1];
        atomicAdd(amp + kk, sqrtf(X.x * X.x + X.y * X.y) * (1.0f / 256.0f));
    }
}

// ---------------------------------------------------------------------------
// Kernel 2: top-2 of amp, derive periods + softmax weights
// ---------------------------------------------------------------------------
__global__ void topk_meta_kernel(const float* __restrict__ amp,
                                 int* __restrict__ mi, float* __restrict__ mf) {
    __shared__ float sv[256];
    __shared__ int   si[256];
    __shared__ float bpv[2];
    __shared__ int   bpi[2];
    const int tid = threadIdx.x;
    for (int pass = 0; pass < 2; ++pass) {
        int excl = (pass == 1) ? bpi[0] : -1;
        float bv = -1e30f; int bi = 1 << 30;
        for (int j = tid; j < N_FREQ; j += 256) {
            if (j == excl) continue;
            float v = amp[j];
            if (v > bv || (v == bv && j < bi)) { bv = v; bi = j; }
        }
        sv[tid] = bv; si[tid] = bi;
        __syncthreads();
        for (int s = 128; s > 0; s >>= 1) {
            if (tid < s) {
                if (sv[tid + s] > sv[tid] ||
                    (sv[tid + s] == sv[tid] && si[tid + s] < si[tid])) {
                    sv[tid] = sv[tid + s]; si[tid] = si[tid + s];
                }
            }
            __syncthreads();
        }
        if (tid == 0) { bpv[pass] = sv[0]; bpi[pass] = si[0]; }
        __syncthreads();
    }
    if (tid == 0) {
        float v1 = bpv[0], v2 = bpv[1];
        int f1 = bpi[0] + 1, f2 = bpi[1] + 1;
        int P1 = (int)llround(2048.0 / (double)f1); if (P1 < 1) P1 = 1;
        int P2 = (int)llround(2048.0 / (double)f2); if (P2 < 1) P2 = 1;
        mi[0] = P1; mi[1] = (T_LEN + P1 - 1) / P1;
        mi[2] = P2; mi[3] = (T_LEN + P2 - 1) / P2;
        float mx = fmaxf(v1, v2);
        float e1 = expf(v1 - mx), e2 = expf(v2 - mx);
        float inv = 1.0f / (e1 + e2);
        mf[4] = e1 * inv; mf[5] = e2 * inv;
    }
}

// ---------------------------------------------------------------------------
// Kernel 3 (fast path, P <= PMAX_FAST): 1D-stencil conv unit.
// CHUNK=512 outputs per block, 2 per thread (t0+tid, t0+tid+256).
// ---------------------------------------------------------------------------
__global__ __launch_bounds__(256) void conv_fast_kernel(
    const float* __restrict__ x,
    const float* __restrict__ w1, const float* __restrict__ b1,
    const float* __restrict__ w2, const float* __restrict__ b2,
    const int* __restrict__ mi, const float* __restrict__ mf,
    float* __restrict__ ws)
{
    const int per  = blockIdx.y;
    const int P    = mi[per * 2 + 0];
    const int cols = mi[per * 2 + 1];
    if (P > PMAX_FAST) return;
    const float wgt = mf[4 + per];
    float* yout = ws + (per == 0 ? WS_Y0 : WS_Y1);

    __shared__ float  xs[1288];           // CHUNK + 4P + 4 <= 1284
    __shared__ float4 hs4[4][HSTRIDE];    // 4 ch-quads x (CHUNK+2P+2 pos + zslot)

    const int tid = threadIdx.x;
    const int b   = blockIdx.x >> 2;
    const int t0  = (blockIdx.x & 3) * CHUNK;
    const int U0  = t0 - (P + 1);            // first h position
    const int HN  = CHUNK + 2 * P + 2;       // h positions incl. halo (<= 898)
    const int X0  = t0 - (2 * P + 2);        // first x stage position
    const int XN  = CHUNK + 4 * P + 4;       // <= 1284

    for (int j = tid; j < XN; j += 256) {
        int t = X0 + j;
        xs[j] = (t >= 0 && t < T_LEN) ? x[b * T_LEN + t] : 0.f;
    }
    if (tid < 4) hs4[tid][ZSLOT] = make_float4(0.f, 0.f, 0.f, 0.f);

    // per-output tap indices for the two outputs this thread owns
    auto mk_idx = [&](int tt, int iout, int* idx) {
        int cc = tt / P;
        int pp = tt - cc * P;
        bool rm = pp > 0, rp = pp < P - 1, cm = cc > 0, cp = (cc + 1) < cols;
        idx[0] = (rm && cm) ? iout - P - 1 : ZSLOT;
        idx[1] = rm         ? iout - 1     : ZSLOT;
        idx[2] = (rm && cp) ? iout + P - 1 : ZSLOT;
        idx[3] = cm         ? iout - P     : ZSLOT;
        idx[4] =              iout;
        idx[5] = cp         ? iout + P     : ZSLOT;
        idx[6] = (rp && cm) ? iout - P + 1 : ZSLOT;
        idx[7] = rp         ? iout + 1     : ZSLOT;
        idx[8] = (rp && cp) ? iout + P + 1 : ZSLOT;
    };
    const int ta = t0 + tid, tb = t0 + tid + 256;
    int idxa[9], idxb[9];
    mk_idx(ta, tid + (P + 1), idxa);
    mk_idx(tb, tid + 256 + (P + 1), idxb);

    // per-position conv1 masks (group-invariant); 4 positions/thread max
    auto posmask = [&](int i) -> int {
        int u = U0 + i;
        int uu = u < 0 ? 0 : u;
        int cc = uu / P;
        int pp = uu - cc * P;
        int rm1 = pp > 0, rp1 = pp < P - 1, cm1 = cc > 0, cp1 = (cc + 1) < cols;
        return (rm1 & cm1) | (rm1 << 1) | ((rm1 & cp1) << 2) | (cm1 << 3) |
               (1 << 4) | (cp1 << 5) | ((rp1 & cm1) << 6) | (rp1 << 7) |
               ((rp1 & cp1) << 8);
    };
    const bool has2 = (tid + 512) < HN;
    const bool has3 = (tid + 768) < HN;
    const int mb0 = posmask(tid);
    const int mb1 = posmask(tid + 256);       // HN >= 516 > 511: always valid
    const int mb2 = has2 ? posmask(tid + 512) : 0;
    const int mb3 = has3 ? posmask(tid + 768) : 0;

    auto do_pos = [&](int i, int mb, int g) {
        const int ibase = i + P + 1;   // xs index of tap center
        float xv[9];
        xv[0] = (mb & 1)   ? xs[ibase - P - 1] : 0.f;
        xv[1] = (mb & 2)   ? xs[ibase - 1]     : 0.f;
        xv[2] = (mb & 4)   ? xs[ibase + P - 1] : 0.f;
        xv[3] = (mb & 8)   ? xs[ibase - P]     : 0.f;
        xv[4] =              xs[ibase];
        xv[5] = (mb & 32)  ? xs[ibase + P]     : 0.f;
        xv[6] = (mb & 64)  ? xs[ibase - P + 1] : 0.f;
        xv[7] = (mb & 128) ? xs[ibase + 1]     : 0.f;
        xv[8] = (mb & 256) ? xs[ibase + P + 1] : 0.f;
        #pragma unroll
        for (int r = 0; r < 4; ++r) {
            float4 hv;
            float* hvp = (float*)&hv;
            #pragma unroll
            for (int e = 0; e < 4; ++e) {
                int ch = g * 16 + r * 4 + e;
                const float* wr = w1 + ch * 9;
                float a = b1[ch];
                #pragma unroll
                for (int k = 0; k < 9; ++k) a = fmaf(wr[k], xv[k], a);
                hvp[e] = gelu_fast(a);
            }
            hs4[r][i] = hv;
        }
    };

    float sa = 0.f, sb = 0.f;
    for (int g = 0; g < 4; ++g) {
        __syncthreads();   // g=0: xs + zero slot ready; g>0: prev conv2 done
        do_pos(tid, mb0, g);
        do_pos(tid + 256, mb1, g);
        if (has2) do_pos(tid + 512, mb2, g);
        if (has3) do_pos(tid + 768, mb3, g);
        __syncthreads();
        #pragma unroll
        for (int r = 0; r < 4; ++r) {
            const float* wr = w2 + (g * 16 + r * 4) * 9;
            #pragma unroll
            for (int k = 0; k < 9; ++k) {
                float w0 = wr[k], w9 = wr[9 + k], w18 = wr[18 + k], w27 = wr[27 + k];
                float4 ha = hs4[r][idxa[k]];
                sa = fmaf(w0, ha.x, sa); sa = fmaf(w9,  ha.y, sa);
                sa = fmaf(w18, ha.z, sa); sa = fmaf(w27, ha.w, sa);
                float4 hb = hs4[r][idxb[k]];
                sb = fmaf(w0, hb.x, sb); sb = fmaf(w9,  hb.y, sb);
                sb = fmaf(w18, hb.z, sb); sb = fmaf(w27, hb.w, sb);
            }
        }
    }
    const float bias2 = b2[0];
    yout[b * T_LEN + ta] = wgt * (sa + bias2);
    yout[b * T_LEN + tb] = wgt * (sb + bias2);
}

// ---------------------------------------------------------------------------
// Kernel 3b (fallback, P > PMAX_FAST): 2D tile version, grid-stride
// ---------------------------------------------------------------------------
__global__ __launch_bounds__(256) void conv_unit_kernel(
    const float* __restrict__ x,
    const float* __restrict__ w1, const float* __restrict__ b1,
    const float* __restrict__ w2, const float* __restrict__ b2,
    const int* __restrict__ mi, const float* __restrict__ mf,
    float* __restrict__ ws)
{
    const int per   = blockIdx.y;
    const int P     = mi[per * 2 + 0];
    const int cols  = mi[per * 2 + 1];
    if (P <= PMAX_FAST) return;
    const float wgt = mf[4 + per];
    float* yout = ws + (per == 0 ? WS_Y0 : WS_Y1);

    __shared__ float w1s[DMODEL * 9];
    __shared__ float w2s[DMODEL * 9];
    __shared__ float b1s[DMODEL];
    __shared__ float xs[12][13];
    __shared__ float hs[DMODEL][101];

    const int tid = threadIdx.x;
    for (int i = tid; i < DMODEL * 9; i += 256) { w1s[i] = w1[i]; w2s[i] = w2[i]; }
    if (tid < DMODEL) b1s[tid] = b1[tid];
    const float bias2 = b2[0];

    const int tp = (P + 7) >> 3;
    const int tc = (cols + 7) >> 3;
    const int tiles_img = tp * tc;
    const int total = tiles_img * NB;

    for (int tile = blockIdx.x; tile < total; tile += gridDim.x) {
        const int b   = tile / tiles_img;
        const int ti  = tile - b * tiles_img;
        const int tpi = ti / tc;
        const int tci = ti - tpi * tc;
        const int p0 = tpi * 8, c0 = tci * 8;

        __syncthreads();
        if (tid < 144) {
            int i = tid / 12, j = tid - (tid / 12) * 12;
            int pp = p0 - 2 + i, cc = c0 - 2 + j;
            float v = 0.f;
            if (pp >= 0 && pp < P && cc >= 0 && cc < cols) {
                int t = cc * P + pp;
                if (t < T_LEN) v = x[b * T_LEN + t];
            }
            xs[i][j] = v;
        }
        __syncthreads();

        #pragma unroll
        for (int it = 0; it < 25; ++it) {
            int idx = it * 256 + tid;
            int ch = idx / 100;
            int px = idx - ch * 100;
            int pi = px / 10;
            int pj = px - pi * 10;
            const float* w = &w1s[ch * 9];
            float a = b1s[ch];
            a = fmaf(w[0], xs[pi    ][pj    ], a);
            a = fmaf(w[1], xs[pi    ][pj + 1], a);
            a = fmaf(w[2], xs[pi    ][pj + 2], a);
            a = fmaf(w[3], xs[pi + 1][pj    ], a);
            a = fmaf(w[4], xs[pi + 1][pj + 1], a);
            a = fmaf(w[5], xs[pi + 1][pj + 2], a);
            a = fmaf(w[6], xs[pi + 2][pj    ], a);
            a = fmaf(w[7], xs[pi + 2][pj + 1], a);
            a = fmaf(w[8], xs[pi + 2][pj + 2], a);
            float g = gelu_fast(a);
            int pp = p0 - 1 + pi, cc = c0 - 1 + pj;
            bool in_img = (pp >= 0) & (pp < P) & (cc >= 0) & (cc < cols);
            hs[ch][px] = in_img ? g : 0.0f;
        }
        __syncthreads();

        {
            const int pixel = tid >> 2, part = tid & 3;
            const int pi = pixel >> 3, pj = pixel & 7;
            const int base = pi * 10 + pj;
            float s = 0.f;
            for (int ch = part * 16; ch < part * 16 + 16; ++ch) {
                const float* w  = &w2s[ch * 9];
                const float* hr = &hs[ch][base];
                s = fmaf(w[0], hr[0],  s);
                s = fmaf(w[1], hr[1],  s);
                s = fmaf(w[2], hr[2],  s);
                s = fmaf(w[3], hr[10], s);
                s = fmaf(w[4], hr[11], s);
                s = fmaf(w[5], hr[12], s);
                s = fmaf(w[6], hr[20], s);
                s = fmaf(w[7], hr[21], s);
                s = fmaf(w[8], hr[22], s);
            }
            s += __shfl_down(s, 1);
            s += __shfl_down(s, 2);
            if (part == 0) {
                int pp = p0 + pi, cc = c0 + pj;
                if (pp < P && cc < cols) {
                    int t = cc * P + pp;
                    if (t < T_LEN) yout[b * T_LEN + t] = wgt * (s + bias2);
                }
            }
        }
    }
}

// ---------------------------------------------------------------------------
// Kernel 4: split-K head GEMM. grid (8, 23, 8): 32x32 out tile, K-chunk 256.
// Partials atomicAdd'ed into out (zeroed by memset); z==0 adds bias.
// ---------------------------------------------------------------------------
__global__ __launch_bounds__(256) void head_gemm_kernel(
    const float* __restrict__ ws, const float* __restrict__ hw,
    const float* __restrict__ hb, float* __restrict__ out)
{
    const float* y0 = ws + WS_Y0;
    const float* y1 = ws + WS_Y1;
    const int b0 = blockIdx.x * 32, h0 = blockIdx.y * 32;
    const int kc0 = blockIdx.z * 256;
    __shared__ float As[32][33];
    __shared__ float Bs[32][33];
    const int tid = threadIdx.x;
    const int tx = tid & 15, ty = tid >> 4;
    const int i0 = ty * 2, j0 = tx * 2;
    float a00 = 0.f, a01 = 0.f, a10 = 0.f, a11 = 0.f;
    for (int k0 = kc0; k0 < kc0 + 256; k0 += 32) {
        #pragma unroll
        for (int e = tid; e < 1024; e += 256) {
            int r = e >> 5, kk = e & 31;
            int src = (b0 + r) * T_LEN + k0 + kk;
            As[r][kk] = y0[src] + y1[src];
            int hrow = h0 + r;
            Bs[r][kk] = (hrow < HORIZON) ? hw[hrow * T_LEN + k0 + kk] : 0.f;
        }
        __syncthreads();
        #pragma unroll
        for (int kk = 0; kk < 32; ++kk) {
            float av0 = As[i0][kk], av1 = As[i0 + 1][kk];
            float bv0 = Bs[j0][kk], bv1 = Bs[j0 + 1][kk];
            a00 = fmaf(av0, bv0, a00); a01 = fmaf(av0, bv1, a01);
            a10 = fmaf(av1, bv0, a10); a11 = fmaf(av1, bv1, a11);
        }
        __syncthreads();
    }
    const int bi = b0 + i0, hj = h0 + j0;
    if (blockIdx.z == 0) {
        if (hj < HORIZON)     { float bb = hb[hj];     a00 += bb; a10 += bb; }
        if (hj + 1 < HORIZON) { float bb = hb[hj + 1]; a01 += bb; a11 += bb; }
    }
    if (hj < HORIZON) {
        atomicAdd(&out[bi * HORIZON + hj], a00);
        atomicAdd(&out[(bi + 1) * HORIZON + hj], a10);
    }
    if (hj + 1 < HORIZON) {
        atomicAdd(&out[bi * HORIZON + hj + 1], a01);
        atomicAdd(&out[(bi + 1) * HORIZON + hj + 1], a11);
    }
}

// ---------------------------------------------------------------------------
extern "C" void kernel_launch(void* const* d_in, const int* in_sizes, int n_in,
                              void* d_out, int out_size, void* d_ws, size_t ws_size,
                              hipStream_t stream) {
    const float* x   = (const float*)d_in[0];
    const float* c1w = (const float*)d_in[1];
    const float* c1b = (const float*)d_in[2];
    const float* c2w = (const float*)d_in[3];
    const float* c2b = (const float*)d_in[4];
    const float* hw  = (const float*)d_in[5];
    const float* hb  = (const float*)d_in[6];
    float* out = (float*)d_out;
    float* ws  = (float*)d_ws;

    float* amp = ws + WS_AMP;
    int*   mi  = (int*)(ws + WS_META);
    float* mf  = ws + WS_META;

    hipMemsetAsync(amp, 0, N_FREQ * sizeof(float), stream);
    hipMemsetAsync(out, 0, (size_t)out_size * sizeof(float), stream);
    fft_amp_kernel<<<NB, 256, 0, stream>>>(x, amp);
    topk_meta_kernel<<<1, 256, 0, stream>>>(amp, mi, mf);
    conv_fast_kernel<<<dim3(NB * 4, 2), 256, 0, stream>>>(x, c1w, c1b, c2w, c2b, mi, mf, ws);
    conv_unit_kernel<<<dim3(1024, 2), 256, 0, stream>>>(x, c1w, c1b, c2w, c2b, mi, mf, ws);
    head_gemm_kernel<<<dim3(NB / 32, (HORIZON + 31) / 32, 8), 256, 0, stream>>>(ws, hw, hb, out);
}

// Round 5
// 215.786 us; speedup vs baseline: 10.7203x; 1.0987x over previous
//
#include <hip/hip_runtime.h>
#include <math.h>

#define T_LEN   2048
#define NB      256
#define N_FREQ  1024
#define DMODEL  64
#define HORIZON 720

// ws layout in floats
#define WS_META 0                     // mi[0..3] ints, mf[4..5] floats
#define WS_AMP  64                    // 1024 floats, zeroed by memset each launch
#define WS_Y0   2048
#define WS_Y1   (2048 + NB * T_LEN)

#define PMAX_FAST 191   // fast conv path handles P <= this; tile kernel covers rest
#define CHUNK   1024    // outputs per block in fast conv (4 per thread)
#define HSTRIDE 1409    // HN_max (1024+2*191+2 = 1408) + zero slot
#define ZSLOT   1408
#define XSMAX   1792    // CHUNK + 4*191 + 4

// cheap tanh-GELU: 0.5*a*(1+tanh(0.79788456*(a+0.044715 a^3))) == a*rcp(1+exp(z)),
// z = a*(c1 + c2*a^2), c1 = -2*0.79788456..., c2 = c1*0.044715
__device__ __forceinline__ float gelu_fast(float a) {
    float a2 = a * a;
    float z  = a * fmaf(-0.07135481627159498f, a2, -1.5957691216057308f);
    float e  = __expf(z);
    return a * __builtin_amdgcn_rcpf(1.0f + e);
}

// ---------------------------------------------------------------------------
// Kernel 1: per-batch 2048-pt complex FFT (radix-2 Stockham, LDS ping-pong),
// 1024 threads = 1 butterfly/thread/stage (16 waves/CU for latency hiding),
// then atomicAdd |X(k)|/256 into amp[k-1] with per-block address rotation.
// ---------------------------------------------------------------------------
__global__ __launch_bounds__(1024) void fft_amp_kernel(const float* __restrict__ x,
                                                       float* __restrict__ amp) {
    __shared__ float2 buf0[2048];
    __shared__ float2 buf1[2048];
    __shared__ float2 tw[1024];
    const int tid = threadIdx.x;
    const int b = blockIdx.x;

    {
        float s, c;
        __sincosf((float)tid * 3.0679615757712823e-3f, &s, &c);  // 2*pi/2048
        tw[tid] = make_float2(c, -s);
    }
    const float* xb = x + b * T_LEN;
    buf0[tid]        = make_float2(xb[tid], 0.f);
    buf0[tid + 1024] = make_float2(xb[tid + 1024], 0.f);
    __syncthreads();

    float2* src = buf0;
    float2* dst = buf1;
    for (int s = 0; s < 11; ++s) {
        const int Ns = 1 << s;
        const int j = tid;
        const int q = j & (Ns - 1);
        const int base = ((j >> s) << (s + 1)) + q;
        float2 a  = src[j];
        float2 bb = src[j + 1024];
        float2 w  = tw[q << (10 - s)];
        float2 t  = make_float2(w.x * bb.x - w.y * bb.y,
                                w.x * bb.y + w.y * bb.x);
        dst[base]      = make_float2(a.x + t.x, a.y + t.y);
        dst[base + Ns] = make_float2(a.x - t.x, a.y - t.y);
        __syncthreads();
        float2* tmp = src; src = dst; dst = tmp;
    }
    // result (natural order) is in src; rotate write order per block
    const int kk = (tid + b * 4) & 1023;   // amp index, freq k = kk+1
    float2 X = src[kk + 1];
    atomicAdd(amp + kk, sqrtf(X.x * X.x + X.y * X.y) * (1.0f / 256.0f));
}

// ---------------------------------------------------------------------------
// Kernel 2: top-2 of amp, derive periods + softmax weights
// ---------------------------------------------------------------------------
__global__ void topk_meta_kernel(const float* __restrict__ amp,
                                 int* __restrict__ mi, float* __restrict__ mf) {
    __shared__ float sv[256];
    __shared__ int   si[256];
    __shared__ float bpv[2];
    __shared__ int   bpi[2];
    const int tid = threadIdx.x;
    for (int pass = 0; pass < 2; ++pass) {
        int excl = (pass == 1) ? bpi[0] : -1;
        float bv = -1e30f; int bi = 1 << 30;
        for (int j = tid; j < N_FREQ; j += 256) {
            if (j == excl) continue;
            float v = amp[j];
            if (v > bv || (v == bv && j < bi)) { bv = v; bi = j; }
        }
        sv[tid] = bv; si[tid] = bi;
        __syncthreads();
        for (int s = 128; s > 0; s >>= 1) {
            if (tid < s) {
                if (sv[tid + s] > sv[tid] ||
                    (sv[tid + s] == sv[tid] && si[tid + s] < si[tid])) {
                    sv[tid] = sv[tid + s]; si[tid] = si[tid + s];
                }
            }
            __syncthreads();
        }
        if (tid == 0) { bpv[pass] = sv[0]; bpi[pass] = si[0]; }
        __syncthreads();
    }
    if (tid == 0) {
        float v1 = bpv[0], v2 = bpv[1];
        int f1 = bpi[0] + 1, f2 = bpi[1] + 1;
        int P1 = (int)llround(2048.0 / (double)f1); if (P1 < 1) P1 = 1;
        int P2 = (int)llround(2048.0 / (double)f2); if (P2 < 1) P2 = 1;
        mi[0] = P1; mi[1] = (T_LEN + P1 - 1) / P1;
        mi[2] = P2; mi[3] = (T_LEN + P2 - 1) / P2;
        float mx = fmaxf(v1, v2);
        float e1 = expf(v1 - mx), e2 = expf(v2 - mx);
        float inv = 1.0f / (e1 + e2);
        mf[4] = e1 * inv; mf[5] = e2 * inv;
    }
}

// ---------------------------------------------------------------------------
// Kernel 3 (fast path, P <= PMAX_FAST): tap-sum factorized 1D-stencil conv.
// o(t) = sum_k dk[k][pos_k(t)], dk[k][u] = sum_ch w2[ch][k]*gelu(conv1(x)[ch][u]).
// h never touches LDS: per position, the 64-ch loop runs in registers and
// accumulates d[9]. Only dk (9 x HSTRIDE floats) + xs are staged. 2 barriers.
// ---------------------------------------------------------------------------
__global__ __launch_bounds__(256) void conv_fast_kernel(
    const float* __restrict__ x,
    const float* __restrict__ w1, const float* __restrict__ b1,
    const float* __restrict__ w2, const float* __restrict__ b2,
    const int* __restrict__ mi, const float* __restrict__ mf,
    float* __restrict__ ws)
{
    const int per  = blockIdx.y;
    const int P    = mi[per * 2 + 0];
    const int cols = mi[per * 2 + 1];
    if (P > PMAX_FAST) return;
    const float wgt = mf[4 + per];
    float* yout = ws + (per == 0 ? WS_Y0 : WS_Y1);

    __shared__ float xs[XSMAX];
    __shared__ float dk[9][HSTRIDE];

    const int tid = threadIdx.x;
    const int b   = blockIdx.x >> 1;
    const int t0  = (blockIdx.x & 1) * CHUNK;
    const int U0  = t0 - (P + 1);            // first h position
    const int HN  = CHUNK + 2 * P + 2;       // h positions incl. halo (<= 1408)
    const int X0  = t0 - (2 * P + 2);        // first x stage position
    const int XN  = CHUNK + 4 * P + 4;       // <= 1792

    for (int j = tid; j < XN; j += 256) {
        int t = X0 + j;
        xs[j] = (t >= 0 && t < T_LEN) ? x[b * T_LEN + t] : 0.f;
    }
    __syncthreads();

    // phase 1: per position, compute 64 h's in registers, accumulate d[9]
    for (int sidx = 0; sidx < 6; ++sidx) {
        const int i = tid + sidx * 256;
        if (i >= HN) break;
        const int u = U0 + i;
        const int uu = u < 0 ? 0 : u;
        const int cc = uu / P;
        const int pp = uu - cc * P;
        const bool rm = pp > 0, rp = pp < P - 1, cm = cc > 0, cp = (cc + 1) < cols;
        const int ibase = i + P + 1;          // xs index of tap center
        float xv[9];
        xv[0] = (rm && cm) ? xs[ibase - P - 1] : 0.f;
        xv[1] = rm         ? xs[ibase - 1]     : 0.f;
        xv[2] = (rm && cp) ? xs[ibase + P - 1] : 0.f;
        xv[3] = cm         ? xs[ibase - P]     : 0.f;
        xv[4] =              xs[ibase];
        xv[5] = cp         ? xs[ibase + P]     : 0.f;
        xv[6] = (rp && cm) ? xs[ibase - P + 1] : 0.f;
        xv[7] = rp         ? xs[ibase + 1]     : 0.f;
        xv[8] = (rp && cp) ? xs[ibase + P + 1] : 0.f;

        float d[9] = {0.f, 0.f, 0.f, 0.f, 0.f, 0.f, 0.f, 0.f, 0.f};
        #pragma unroll 4
        for (int ch = 0; ch < DMODEL; ++ch) {
            const float* wr1 = w1 + ch * 9;
            float a = b1[ch];
            #pragma unroll
            for (int k = 0; k < 9; ++k) a = fmaf(wr1[k], xv[k], a);
            float h = gelu_fast(a);
            const float* wr2 = w2 + ch * 9;
            #pragma unroll
            for (int k = 0; k < 9; ++k) d[k] = fmaf(wr2[k], h, d[k]);
        }
        #pragma unroll
        for (int k = 0; k < 9; ++k) dk[k][i] = d[k];
    }
    if (tid < 9) dk[tid][ZSLOT] = 0.f;
    __syncthreads();

    // phase 2: gather 9 tap-sums per output
    const float bias2 = b2[0];
    #pragma unroll
    for (int o = 0; o < 4; ++o) {
        const int t = t0 + tid + o * 256;
        const int iout = tid + o * 256 + (P + 1);
        const int cc = t / P;
        const int pp = t - cc * P;
        const bool rm = pp > 0, rp = pp < P - 1, cm = cc > 0, cp = (cc + 1) < cols;
        const int i0 = (rm && cm) ? iout - P - 1 : ZSLOT;
        const int i1 = rm         ? iout - 1     : ZSLOT;
        const int i2 = (rm && cp) ? iout + P - 1 : ZSLOT;
        const int i3 = cm         ? iout - P     : ZSLOT;
        const int i5 = cp         ? iout + P     : ZSLOT;
        const int i6 = (rp && cm) ? iout - P + 1 : ZSLOT;
        const int i7 = rp         ? iout + 1     : ZSLOT;
        const int i8 = (rp && cp) ? iout + P + 1 : ZSLOT;
        float s = dk[4][iout];
        s += dk[0][i0]; s += dk[1][i1]; s += dk[2][i2];
        s += dk[3][i3]; s += dk[5][i5]; s += dk[6][i6];
        s += dk[7][i7]; s += dk[8][i8];
        yout[b * T_LEN + t] = wgt * (s + bias2);
    }
}

// ---------------------------------------------------------------------------
// Kernel 3b (fallback, P > PMAX_FAST): 2D tile version, grid-stride
// ---------------------------------------------------------------------------
__global__ __launch_bounds__(256) void conv_unit_kernel(
    const float* __restrict__ x,
    const float* __restrict__ w1, const float* __restrict__ b1,
    const float* __restrict__ w2, const float* __restrict__ b2,
    const int* __restrict__ mi, const float* __restrict__ mf,
    float* __restrict__ ws)
{
    const int per   = blockIdx.y;
    const int P     = mi[per * 2 + 0];
    const int cols  = mi[per * 2 + 1];
    if (P <= PMAX_FAST) return;
    const float wgt = mf[4 + per];
    float* yout = ws + (per == 0 ? WS_Y0 : WS_Y1);

    __shared__ float w1s[DMODEL * 9];
    __shared__ float w2s[DMODEL * 9];
    __shared__ float b1s[DMODEL];
    __shared__ float xs[12][13];
    __shared__ float hs[DMODEL][101];

    const int tid = threadIdx.x;
    for (int i = tid; i < DMODEL * 9; i += 256) { w1s[i] = w1[i]; w2s[i] = w2[i]; }
    if (tid < DMODEL) b1s[tid] = b1[tid];
    const float bias2 = b2[0];

    const int tp = (P + 7) >> 3;
    const int tc = (cols + 7) >> 3;
    const int tiles_img = tp * tc;
    const int total = tiles_img * NB;

    for (int tile = blockIdx.x; tile < total; tile += gridDim.x) {
        const int b   = tile / tiles_img;
        const int ti  = tile - b * tiles_img;
        const int tpi = ti / tc;
        const int tci = ti - tpi * tc;
        const int p0 = tpi * 8, c0 = tci * 8;

        __syncthreads();
        if (tid < 144) {
            int i = tid / 12, j = tid - (tid / 12) * 12;
            int pp = p0 - 2 + i, cc = c0 - 2 + j;
            float v = 0.f;
            if (pp >= 0 && pp < P && cc >= 0 && cc < cols) {
                int t = cc * P + pp;
                if (t < T_LEN) v = x[b * T_LEN + t];
            }
            xs[i][j] = v;
        }
        __syncthreads();

        #pragma unroll
        for (int it = 0; it < 25; ++it) {
            int idx = it * 256 + tid;
            int ch = idx / 100;
            int px = idx - ch * 100;
            int pi = px / 10;
            int pj = px - pi * 10;
            const float* w = &w1s[ch * 9];
            float a = b1s[ch];
            a = fmaf(w[0], xs[pi    ][pj    ], a);
            a = fmaf(w[1], xs[pi    ][pj + 1], a);
            a = fmaf(w[2], xs[pi    ][pj + 2], a);
            a = fmaf(w[3], xs[pi + 1][pj    ], a);
            a = fmaf(w[4], xs[pi + 1][pj + 1], a);
            a = fmaf(w[5], xs[pi + 1][pj + 2], a);
            a = fmaf(w[6], xs[pi + 2][pj    ], a);
            a = fmaf(w[7], xs[pi + 2][pj + 1], a);
            a = fmaf(w[8], xs[pi + 2][pj + 2], a);
            float g = gelu_fast(a);
            int pp = p0 - 1 + pi, cc = c0 - 1 + pj;
            bool in_img = (pp >= 0) & (pp < P) & (cc >= 0) & (cc < cols);
            hs[ch][px] = in_img ? g : 0.0f;
        }
        __syncthreads();

        {
            const int pixel = tid >> 2, part = tid & 3;
            const int pi = pixel >> 3, pj = pixel & 7;
            const int base = pi * 10 + pj;
            float s = 0.f;
            for (int ch = part * 16; ch < part * 16 + 16; ++ch) {
                const float* w  = &w2s[ch * 9];
                const float* hr = &hs[ch][base];
                s = fmaf(w[0], hr[0],  s);
                s = fmaf(w[1], hr[1],  s);
                s = fmaf(w[2], hr[2],  s);
                s = fmaf(w[3], hr[10], s);
                s = fmaf(w[4], hr[11], s);
                s = fmaf(w[5], hr[12], s);
                s = fmaf(w[6], hr[20], s);
                s = fmaf(w[7], hr[21], s);
                s = fmaf(w[8], hr[22], s);
            }
            s += __shfl_down(s, 1);
            s += __shfl_down(s, 2);
            if (part == 0) {
                int pp = p0 + pi, cc = c0 + pj;
                if (pp < P && cc < cols) {
                    int t = cc * P + pp;
                    if (t < T_LEN) yout[b * T_LEN + t] = wgt * (s + bias2);
                }
            }
        }
    }
}

// ---------------------------------------------------------------------------
// Kernel 4: split-K head GEMM. grid (8, 23, 8): 32x32 out tile, K-chunk 256.
// Partials atomicAdd'ed into out (zeroed by memset); z==0 adds bias.
// ---------------------------------------------------------------------------
__global__ __launch_bounds__(256) void head_gemm_kernel(
    const float* __restrict__ ws, const float* __restrict__ hw,
    const float* __restrict__ hb, float* __restrict__ out)
{
    const float* y0 = ws + WS_Y0;
    const float* y1 = ws + WS_Y1;
    const int b0 = blockIdx.x * 32, h0 = blockIdx.y * 32;
    const int kc0 = blockIdx.z * 256;
    __shared__ float As[32][33];
    __shared__ float Bs[32][33];
    const int tid = threadIdx.x;
    const int tx = tid & 15, ty = tid >> 4;
    const int i0 = ty * 2, j0 = tx * 2;
    float a00 = 0.f, a01 = 0.f, a10 = 0.f, a11 = 0.f;
    for (int k0 = kc0; k0 < kc0 + 256; k0 += 32) {
        #pragma unroll
        for (int e = tid; e < 1024; e += 256) {
            int r = e >> 5, kk = e & 31;
            int src = (b0 + r) * T_LEN + k0 + kk;
            As[r][kk] = y0[src] + y1[src];
            int hrow = h0 + r;
            Bs[r][kk] = (hrow < HORIZON) ? hw[hrow * T_LEN + k0 + kk] : 0.f;
        }
        __syncthreads();
        #pragma unroll
        for (int kk = 0; kk < 32; ++kk) {
            float av0 = As[i0][kk], av1 = As[i0 + 1][kk];
            float bv0 = Bs[j0][kk], bv1 = Bs[j0 + 1][kk];
            a00 = fmaf(av0, bv0, a00); a01 = fmaf(av0, bv1, a01);
            a10 = fmaf(av1, bv0, a10); a11 = fmaf(av1, bv1, a11);
        }
        __syncthreads();
    }
    const int bi = b0 + i0, hj = h0 + j0;
    if (blockIdx.z == 0) {
        if (hj < HORIZON)     { float bb = hb[hj];     a00 += bb; a10 += bb; }
        if (hj + 1 < HORIZON) { float bb = hb[hj + 1]; a01 += bb; a11 += bb; }
    }
    if (hj < HORIZON) {
        atomicAdd(&out[bi * HORIZON + hj], a00);
        atomicAdd(&out[(bi + 1) * HORIZON + hj], a10);
    }
    if (hj + 1 < HORIZON) {
        atomicAdd(&out[bi * HORIZON + hj + 1], a01);
        atomicAdd(&out[(bi + 1) * HORIZON + hj + 1], a11);
    }
}

// ---------------------------------------------------------------------------
extern "C" void kernel_launch(void* const* d_in, const int* in_sizes, int n_in,
                              void* d_out, int out_size, void* d_ws, size_t ws_size,
                              hipStream_t stream) {
    const float* x   = (const float*)d_in[0];
    const float* c1w = (const float*)d_in[1];
    const float* c1b = (const float*)d_in[2];
    const float* c2w = (const float*)d_in[3];
    const float* c2b = (const float*)d_in[4];
    const float* hw  = (const float*)d_in[5];
    const float* hb  = (const float*)d_in[6];
    float* out = (float*)d_out;
    float* ws  = (float*)d_ws;

    float* amp = ws + WS_AMP;
    int*   mi  = (int*)(ws + WS_META);
    float* mf  = ws + WS_META;

    hipMemsetAsync(amp, 0, N_FREQ * sizeof(float), stream);
    hipMemsetAsync(out, 0, (size_t)out_size * sizeof(float), stream);
    fft_amp_kernel<<<NB, 1024, 0, stream>>>(x, amp);
    topk_meta_kernel<<<1, 256, 0, stream>>>(amp, mi, mf);
    conv_fast_kernel<<<dim3(NB * 2, 2), 256, 0, stream>>>(x, c1w, c1b, c2w, c2b, mi, mf, ws);
    conv_unit_kernel<<<dim3(1024, 2), 256, 0, stream>>>(x, c1w, c1b, c2w, c2b, mi, mf, ws);
    head_gemm_kernel<<<dim3(NB / 32, (HORIZON + 31) / 32, 8), 256, 0, stream>>>(ws, hw, hb, out);
}